// Round 8
// baseline (1496.905 us; speedup 1.0000x reference)
//
#include <hip/hip_runtime.h>
#include <cstdint>
#include <cstddef>

// Problem dims: B=4, H=192, W=640, C=64, sr=2
// Conv chans: 69 -> 128 -> 128 -> 96 -> 64 -> 32 -> 1, 3x3 SAME, NHWC/HWIO.
//
// R12 (4 blocks/CU): 1377us — FETCH 584MB @3.1TB/s: per-XCD live row set
// 4.2MB > 4MB L2 -> halo/weight re-reads miss; L2-miss-BW-bound. Occupancy
// ceiling for this working set = 3 blocks/CU (R6: FETCH 80MB, 189us hot).
// R13 = 3 blocks/CU (LDS padded to 42KB to pin it) + compiler-proof
// counted-vmcnt B pipeline:
//  - B loads via volatile inline-asm global_load_dwordx4 (cannot be sunk,
//    unlike R7's C++ prefetch which the compiler collapsed)
//  - s_waitcnt vmcnt(NL) with NL = exact loads-in-flight for next buffer;
//    sched_barrier(0) after each wait (rule #18)
//  - uniform vm count per wave (clamped tile for conv3's phantom)
//  - stage DMA + step-0 B prefetch drained by __syncthreads vmcnt(0), so
//    the in-loop queue holds only B loads -> counting exact.

#define LEAKY_SLOPE 0.2f

typedef float  f32x16 __attribute__((ext_vector_type(16)));
typedef short  s16x8  __attribute__((ext_vector_type(8)));
typedef short  s16x4  __attribute__((ext_vector_type(4)));

__device__ __forceinline__ unsigned short f2bf(float f) {
    unsigned u = __float_as_uint(f);
    u += 0x7FFFu + ((u >> 16) & 1u);          // round-to-nearest-even
    return (unsigned short)(u >> 16);
}
__device__ __forceinline__ float bf2f(unsigned short s) {
    return __uint_as_float(((unsigned)s) << 16);
}
__device__ __forceinline__ float leaky(float v){ return v >= 0.f ? v : LEAKY_SLOPE * v; }

// async 16B global->LDS DMA (gfx950). LDS dest = wave-uniform base + lane*16.
__device__ __forceinline__ void async16(const void* g, void* l) {
    __builtin_amdgcn_global_load_lds(
        (__attribute__((address_space(1))) void*)g,
        (__attribute__((address_space(3))) void*)l, 16, 0, 0);
}

// volatile-asm 16B global load: issue position is fixed (cannot be sunk);
// completion is governed by the explicit counted s_waitcnt below.
__device__ __forceinline__ s16x8 gload16(const short* p) {
    s16x8 r;
    asm volatile("global_load_dwordx4 %0, %1, off" : "=v"(r) : "v"(p));
    return r;
}

// counted vmcnt wait + full scheduling fence (rule #18: MFMA must not be
// hoisted past an inline-asm waitcnt; VALU copies of B regs must not cross).
template <int N>
__device__ __forceinline__ void wait_vm() {
    if constexpr (N == 0)      asm volatile("s_waitcnt vmcnt(0)" ::: "memory");
    else if constexpr (N == 2) asm volatile("s_waitcnt vmcnt(2)" ::: "memory");
    else if constexpr (N == 3) asm volatile("s_waitcnt vmcnt(3)" ::: "memory");
    else if constexpr (N == 6) asm volatile("s_waitcnt vmcnt(6)" ::: "memory");
    else if constexpr (N == 8) asm volatile("s_waitcnt vmcnt(8)" ::: "memory");
    else static_assert(N == 0 || N == 2 || N == 3 || N == 6 || N == 8, "NL");
    __builtin_amdgcn_sched_barrier(0);
}

// Bijective XCD swizzle (m204): contiguous work-chunk per XCD.
__device__ __forceinline__ int xcd_swizzle(int f, int T) {
    const int q = T >> 3, r = T & 7;
    const int xcd = f & 7, i = f >> 3;
    return (xcd < r ? xcd * (q + 1) : r * (q + 1) + (xcd - r) * q) + i;
}

// ---------------------------------------------------------------------------
// Pack HWIO fp32 weights into bf16 B-fragment order for mfma_32x32x16_bf16:
// flat = (((dydx*KB + kb)*NT + nt)*64 + lane)*8 + j
// value = w[dydx][ci = kb*16 + (lane>>5)*8 + j][co = nt*32 + (lane&31)]
// ---------------------------------------------------------------------------
__global__ __launch_bounds__(256) void pack_weights(
    const float* __restrict__ src, short* __restrict__ dst,
    int CIN, int COUT, int KB, int NT, int total)
{
    int i = blockIdx.x * 256 + threadIdx.x;
    if (i >= total) return;
    int j    = i & 7;
    int lane = (i >> 3) & 63;
    int r    = i >> 9;
    int nt = r % NT; r /= NT;
    int kb = r % KB;
    int dydx = r / KB;
    int ci = kb * 16 + ((lane >> 5) << 3) + j;
    int co = nt * 32 + (lane & 31);
    float v = (ci < CIN) ? src[((size_t)dydx * CIN + ci) * COUT + co] : 0.f;
    dst[i] = (short)f2bf(v);
}

__global__ __launch_bounds__(64) void zero_fill(short* p) {
    p[threadIdx.x] = 0;
}

// ---------------------------------------------------------------------------
// Fused upsample + warp + cost-volume. Block = 64 px (one xt) of one row.
// Output layout (tiled-96): obase + (tile*64 + px)*32 + co, tiles:
//   tile0 = left ch 0..31, tile1 = left ch 32..63,
//   tile2: co 0..4 = cost dots, co 5..31 = zero.
// ---------------------------------------------------------------------------
__global__ __launch_bounds__(256) void warp_costs_kernel(
    const float* __restrict__ left, const float* __restrict__ right,
    const float* __restrict__ prev, short* __restrict__ out,
    int H, int W)
{
    __shared__ float wt0s[68], wt1s[68];
    __shared__ int   i0s[68],  i1s[68];
    __shared__ __align__(16) short warp_s[68 * 72];  // [px -2..65][64ch]
    __shared__ __align__(16) short left_s[64 * 72];

    const int tid = threadIdx.x;
    const int w0 = blockIdx.x * 64;
    const int hh = blockIdx.y % H;
    const int bb = blockIdx.y / H;
    const int H2 = H >> 1, W2 = W >> 1;

    if (tid < 68) {
        int w = w0 - 2 + tid;
        float sy = 0.5f * (float)hh - 0.25f;
        float sx = 0.5f * (float)w  - 0.25f;
        float y0f = floorf(sy), x0f = floorf(sx);
        float fy = sy - y0f, fx = sx - x0f;
        int y0 = (int)y0f, x0 = (int)x0f;
        int y0c = min(max(y0, 0), H2 - 1), y1c = min(max(y0 + 1, 0), H2 - 1);
        int x0c = min(max(x0, 0), W2 - 1), x1c = min(max(x0 + 1, 0), W2 - 1);
        const float* pb = prev + (size_t)bb * H2 * W2;
        float p00 = pb[y0c * W2 + x0c], p01 = pb[y0c * W2 + x1c];
        float p10 = pb[y1c * W2 + x0c], p11 = pb[y1c * W2 + x1c];
        float disp = (1.f - fy) * ((1.f - fx) * p00 + fx * p01)
                   + fy * ((1.f - fx) * p10 + fx * p11);
        float cx = (float)w + disp;
        float xf0 = floorf(cx), xf1 = xf0 + 1.f;
        float xmax = (float)(W - 1);
        float x0s = fminf(fmaxf(xf0, 0.f), xmax);
        float x1s = fminf(fmaxf(xf1, 0.f), xmax);
        wt0s[tid] = (xf1 - cx) * (xf0 == x0s ? 1.f : 0.f);
        wt1s[tid] = (cx - xf0) * (xf1 == x1s ? 1.f : 0.f);
        i0s[tid] = (int)x0s;
        i1s[tid] = (int)x1s;
    }
    __syncthreads();

    const float* rrow = right + (size_t)(bb * H + hh) * W * 64;
    const float* lrow = left  + (size_t)(bb * H + hh) * W * 64;
    const size_t obase = ((size_t)(bb * H + hh) * W + w0) * 96;

    for (int u = tid; u < 68 * 16; u += 256) {
        int px = u >> 4, c4 = (u & 15) * 4;
        float a = wt0s[px], b = wt1s[px];
        const float4 r0 = *(const float4*)(rrow + (size_t)i0s[px] * 64 + c4);
        const float4 r1 = *(const float4*)(rrow + (size_t)i1s[px] * 64 + c4);
        s16x4 o;
        o[0] = (short)f2bf(a * r0.x + b * r1.x);
        o[1] = (short)f2bf(a * r0.y + b * r1.y);
        o[2] = (short)f2bf(a * r0.z + b * r1.z);
        o[3] = (short)f2bf(a * r0.w + b * r1.w);
        *(s16x4*)(warp_s + px * 72 + c4) = o;
    }
    for (int u = tid; u < 64 * 16; u += 256) {
        int px = u >> 4, c4 = (u & 15) * 4;
        const float4 l = *(const float4*)(lrow + ((size_t)(w0 + px)) * 64 + c4);
        s16x4 o;
        o[0] = (short)f2bf(l.x);
        o[1] = (short)f2bf(l.y);
        o[2] = (short)f2bf(l.z);
        o[3] = (short)f2bf(l.w);
        *(s16x4*)(left_s + px * 72 + c4) = o;
        // tiled store: tile = c4>>5, co = c4&31
        *(s16x4*)(out + obase + ((size_t)((c4 >> 5) * 64 + px)) * 32 + (c4 & 31)) = o;
    }
    // zero tile2 (ch 64..95) fully: 2048 contiguous shorts at obase+4096
    {
        s16x8 z = {0,0,0,0,0,0,0,0};
        *(s16x8*)(out + obase + 4096 + (size_t)tid * 8) = z;
    }
    __syncthreads();

    // cost dots: 320 (px,d) tasks -> tile2 co d (ordered after zero via barrier)
    for (int u = tid; u < 64 * 5; u += 256) {
        int px = u / 5, d = u - px * 5;
        int x = w0 + px + d - 2;
        float s = 0.f;
        if (x >= 0 && x < W) {
            const short* lp = left_s + px * 72;
            const short* wq = warp_s + (px + d) * 72;
#pragma unroll
            for (int c8 = 0; c8 < 8; ++c8) {
                s16x8 l8 = *(const s16x8*)(lp + c8 * 8);
                s16x8 w8 = *(const s16x8*)(wq + c8 * 8);
#pragma unroll
                for (int k = 0; k < 8; ++k)
                    s += bf2f((unsigned short)l8[k]) * bf2f((unsigned short)w8[k]);
            }
        }
        out[obase + 4096 + (size_t)px * 32 + d] = (short)f2bf(s * (1.f / 64.f));
    }
}

// ---------------------------------------------------------------------------
// bf16 MFMA 3x3 conv (implicit GEMM, mfma_f32_32x32x16_bf16).
// Block = 128 px of one row x all COUT. Waves WM x WN. 3 blocks/CU pinned
// via LDS pad (42KB; conv5 21.4KB -> 7 blocks). Per dy: barrier; DMA-stage
// row + prefetch step-0 B; barrier (drains all); 6 half-chunk steps with
// asm B loads double-buffered + counted vmcnt + sched_barrier.
// Activations tiled [h][xt][cotile][px64][co32].
// ---------------------------------------------------------------------------
template <int CINP, int COUT, int TPB, bool RELU>
__global__ __launch_bounds__(TPB, 3) void conv_mfma(
    const short* __restrict__ in, const short* __restrict__ wp,
    const float* __restrict__ bias, short* __restrict__ out,
    const short* __restrict__ zerobuf, int H, int W)
{
    constexpr int KB   = CINP / 16;                  // K-steps per (dy,dx)
    constexpr int HK   = KB / 2;                     // half-chunk depth
    constexpr int NT   = COUT / 32;                  // n-tiles total
    constexpr int TI   = CINP / 32;                  // input co-tiles
    constexpr int CIN8 = CINP / 8;
    constexpr int SL8  = (CIN8 == 12) ? 16 : CIN8;   // LDS ch8-slots/px (pow2)
    constexpr int SH   = (SL8 == 16) ? 4 : 3;        // log2(SL8)
    constexpr int WN   = (NT >= 2) ? 2 : 1;          // n-split ways
    constexpr int WM   = (TPB / 64) / WN;            // m-split ways
    constexpr int MT   = 4 / WM;                     // m-tiles per wave
    constexpr int NTW  = (NT + WN - 1) / WN;         // n-tiles per wave
    constexpr int NL   = HK * NTW;                   // B loads per half-chunk
    constexpr int TASKS = 130 * SL8;                 // 16B stage tasks/row
    constexpr int NITER = (TASKS + TPB - 1) / TPB;
    constexpr int BUFS  = TASKS * 8;                 // shorts in row buffer
    // pad LDS to pin blocks/CU: 42000B -> 3 (conv1-4), 21400B -> 7 (conv5)
    constexpr int LDSN  = (CINP == 64) ? 10700 : 21000;
    static_assert(BUFS <= LDSN, "pad");
    __shared__ __align__(16) short lds[LDSN];

    const int tid  = threadIdx.x;
    const int lane = tid & 63;
    const int wave = tid >> 6;
    const int wn   = wave % WN;
    const int wm   = wave / WN;
    const int l31  = lane & 31;
    const int lhi  = lane >> 5;

    // XCD-aware remap (bijective): contiguous rows per XCD, x fastest.
    const int nbx  = gridDim.x;
    const int work = xcd_swizzle(blockIdx.y * nbx + blockIdx.x,
                                 nbx * gridDim.y);
    const int w0 = (work % nbx) * 128;
    const int by = work / nbx;
    const int hh = by % H;
    const int bb = by / H;

    // stage input row H_ into the row buffer (DMA; tiled dense source):
    // addr = rowbase + ((x>>6)*TI + (sc>>2))*2048 + (x&63)*32 + (sc&3)*8
#define ISSUE_STAGE(H_) do {                                               \
        const int h_ = (H_);                                               \
        const bool rowok_ = (h_ >= 0) && (h_ < H);                         \
        const size_t rb_ = (size_t)(bb * H + (rowok_ ? h_ : 0)) * W * CINP;\
        _Pragma("unroll")                                                  \
        for (int k_ = 0; k_ < NITER; ++k_) {                               \
            const int u_  = tid + k_ * TPB;                                \
            const int px_ = u_ >> SH;                                      \
            const int sc_ = (u_ & (SL8 - 1)) ^ (px_ & 7);                  \
            const int x_  = w0 - 1 + px_;                                  \
            if (u_ < TASKS && sc_ < CIN8) {                                \
                const bool ok_ = rowok_ && (x_ >= 0) && (x_ < W);          \
                const int xc_ = ok_ ? x_ : 0;                              \
                const short* g_ = ok_                                      \
                    ? (in + rb_ + ((xc_ >> 6) * TI + (sc_ >> 2)) * 2048    \
                             + (xc_ & 63) * 32 + (sc_ & 3) * 8)            \
                    : zerobuf;                                             \
                async16(g_, lds + (size_t)(u_ - lane) * 8);                \
            }                                                              \
        }                                                                  \
    } while (0)

    // issue NL asm B loads for half-chunk (DY,DX,H0) into BUF. Tile index
    // clamped so every wave issues exactly NL loads (uniform vmcnt).
#define ISSUE_B(BUF, DY, DX, H0) do {                                      \
        const short* wdx_ = wlane + (size_t)(((DY) * 3 + (DX)) * KB) * NT * 512; \
        _Pragma("unroll")                                                  \
        for (int kk_ = 0; kk_ < HK; ++kk_)                                 \
        _Pragma("unroll")                                                  \
        for (int j_ = 0; j_ < NTW; ++j_) {                                 \
            const int t_  = wn * NTW + j_;                                 \
            const int tc_ = (t_ < NT) ? t_ : (NT - 1);                     \
            BUF[kk_][j_] = gload16(wdx_ + (size_t)((((H0) * HK + kk_) * NT + tc_)) * 512); \
        }                                                                  \
    } while (0)

    // HK k-steps of one half-chunk: A from LDS, B from BUF (resident).
#define MFMA_HALF(BUF, DX, H0) do {                                        \
        _Pragma("unroll")                                                  \
        for (int kk_ = 0; kk_ < HK; ++kk_) {                               \
            const int kb_  = (H0) * HK + kk_;                              \
            const int c8r_ = kb_ * 2 + lhi;                                \
            s16x8 a_[MT];                                                  \
            _Pragma("unroll")                                              \
            for (int mt_ = 0; mt_ < MT; ++mt_) {                           \
                const int px_ = (wm * MT + mt_) * 32 + l31 + (DX);         \
                a_[mt_] = *(const s16x8*)(&lds[(px_ * SL8 + (c8r_ ^ (px_ & 7))) * 8]); \
            }                                                              \
            _Pragma("unroll")                                              \
            for (int j_ = 0; j_ < NTW; ++j_) {                             \
                if (wn * NTW + j_ >= NT) continue;                         \
                _Pragma("unroll")                                          \
                for (int mt_ = 0; mt_ < MT; ++mt_)                         \
                    acc[mt_][j_] = __builtin_amdgcn_mfma_f32_32x32x16_bf16( \
                        a_[mt_], BUF[kk_][j_], acc[mt_][j_], 0, 0, 0);     \
            }                                                              \
        }                                                                  \
    } while (0)

    f32x16 acc[MT][NTW];
#pragma unroll
    for (int mt = 0; mt < MT; ++mt)
#pragma unroll
        for (int j = 0; j < NTW; ++j)
#pragma unroll
            for (int r = 0; r < 16; ++r) acc[mt][j][r] = 0.f;

    const short* wlane = wp + (size_t)lane * 8;
    s16x8 bA[HK][NTW], bB[HK][NTW];

    for (int dy = 0; dy < 3; ++dy) {
        __syncthreads();               // readers of previous row done
        ISSUE_STAGE(hh + dy - 1);      // row DMA (drained at next barrier)
        ISSUE_B(bA, dy, 0, 0);         // step-0 B prefetch (drained too)
        __syncthreads();               // vmcnt(0): row + bA resident
        // 6 half-chunk steps; queue now holds only B loads -> exact counts.
        ISSUE_B(bB, dy, 0, 1); wait_vm<NL>(); MFMA_HALF(bA, 0, 0);
        ISSUE_B(bA, dy, 1, 0); wait_vm<NL>(); MFMA_HALF(bB, 0, 1);
        ISSUE_B(bB, dy, 1, 1); wait_vm<NL>(); MFMA_HALF(bA, 1, 0);
        ISSUE_B(bA, dy, 2, 0); wait_vm<NL>(); MFMA_HALF(bB, 1, 1);
        ISSUE_B(bB, dy, 2, 1); wait_vm<NL>(); MFMA_HALF(bA, 2, 0);
        wait_vm<0>();                         MFMA_HALF(bB, 2, 1);
    }
#undef ISSUE_STAGE
#undef ISSUE_B
#undef MFMA_HALF

    // epilogue: tiled stores. C/D: co=l31, px64=(v&3)+8*(v>>2)+4*lhi.
    const size_t outrow = (size_t)(bb * H + hh) * W * COUT;
    const int xtb = w0 >> 6;
#pragma unroll
    for (int j = 0; j < NTW; ++j) {
        const int tile = wn * NTW + j;
        if (tile >= NT) continue;
        const float bv = bias[tile * 32 + l31];
#pragma unroll
        for (int mt = 0; mt < MT; ++mt) {
            const int mtile = wm * MT + mt;
            const int xt   = xtb + (mtile >> 1);
            const int pxb  = (mtile & 1) * 32 + 4 * lhi;
            const size_t tbase = outrow + (size_t)((xt * NT + tile) * 64) * 32;
#pragma unroll
            for (int v = 0; v < 16; ++v) {
                const int px64 = pxb + (v & 3) + 8 * (v >> 2);
                float val = acc[mt][j][v] + bv;
                if (RELU) val = leaky(val);
                out[tbase + px64 * 32 + l31] = (short)f2bf(val);
            }
        }
    }
}

// ---------------------------------------------------------------------------
// Final conv 32 -> 1, linear, bf16 in / fp32 out. One thread per pixel.
// (tiled-32 layout == NHWC, so addressing unchanged.)
// ---------------------------------------------------------------------------
__global__ __launch_bounds__(256) void conv_last_kernel(
    const short* __restrict__ in, const float* __restrict__ wgt,
    const float* __restrict__ bias, float* __restrict__ out,
    int H, int W, int npx)
{
    int blk = xcd_swizzle(blockIdx.x, gridDim.x);
    int idx = blk * 256 + threadIdx.x;
    if (idx >= npx) return;
    int w = idx % W;
    int t = idx / W;
    int h = t % H;
    int b = t / H;

    float acc = bias[0];
#pragma unroll
    for (int dy = 0; dy < 3; ++dy) {
        int hy = h + dy - 1;
        if (hy < 0 || hy >= H) continue;
#pragma unroll
        for (int dx = 0; dx < 3; ++dx) {
            int x = w + dx - 1;
            if (x < 0 || x >= W) continue;
            const short* p = in + ((size_t)(b * H + hy) * W + x) * 32;
            const float* wk = wgt + (dy * 3 + dx) * 32;
#pragma unroll
            for (int c8 = 0; c8 < 4; ++c8) {
                s16x8 v = *(const s16x8*)(p + c8 * 8);
#pragma unroll
                for (int k = 0; k < 8; ++k)
                    acc += bf2f((unsigned short)v[k]) * wk[c8 * 8 + k];
            }
        }
    }
    out[idx] = acc;
}

// ---------------------------------------------------------------------------
extern "C" void kernel_launch(void* const* d_in, const int* in_sizes, int n_in,
                              void* d_out, int out_size, void* d_ws, size_t ws_size,
                              hipStream_t stream)
{
    constexpr int B = 4, H = 192, W = 640;
    constexpr int HW = H * W;          // 122880

    const float* left  = (const float*)d_in[0];
    const float* right = (const float*)d_in[1];
    const float* prev  = (const float*)d_in[2];
    const float* w1 = (const float*)d_in[4];
    const float* b1 = (const float*)d_in[5];
    const float* w2 = (const float*)d_in[6];
    const float* b2 = (const float*)d_in[7];
    const float* w3 = (const float*)d_in[8];
    const float* b3 = (const float*)d_in[9];
    const float* w4 = (const float*)d_in[10];
    const float* b4 = (const float*)d_in[11];
    const float* w5 = (const float*)d_in[12];
    const float* b5 = (const float*)d_in[13];
    const float* w6 = (const float*)d_in[14];
    const float* b6 = (const float*)d_in[15];
    float* out = (float*)d_out;

    // Packed-weight region (shorts), then bf16 activation ping-pong X/Y.
    constexpr int S1 = 9 * 6 * 4 * 512;   // conv1: CINP 96,  COUT 128
    constexpr int S2 = 9 * 8 * 4 * 512;   // conv2: 128 -> 128
    constexpr int S3 = 9 * 8 * 3 * 512;   // conv3: 128 -> 96
    constexpr int S4 = 9 * 6 * 2 * 512;   // conv4: 96  -> 64
    constexpr int S5 = 9 * 4 * 1 * 512;   // conv5: 64  -> 32
    constexpr int P1 = 0, P2 = P1 + S1, P3 = P2 + S2, P4 = P3 + S3, P5 = P4 + S4;
    constexpr size_t WPAD = 524288;       // 1 MiB reserved (in shorts)
    constexpr size_t ZOFF = WPAD - 64;    // 128B zero region for DMA redirect

    short* wsS = (short*)d_ws;
    pack_weights<<<(S1 + 255) / 256, 256, 0, stream>>>(w1, wsS + P1,  69, 128, 6, 4, S1);
    pack_weights<<<(S2 + 255) / 256, 256, 0, stream>>>(w2, wsS + P2, 128, 128, 8, 4, S2);
    pack_weights<<<(S3 + 255) / 256, 256, 0, stream>>>(w3, wsS + P3, 128,  96, 8, 3, S3);
    pack_weights<<<(S4 + 255) / 256, 256, 0, stream>>>(w4, wsS + P4,  96,  64, 6, 2, S4);
    pack_weights<<<(S5 + 255) / 256, 256, 0, stream>>>(w5, wsS + P5,  64,  32, 4, 1, S5);
    zero_fill<<<1, 64, 0, stream>>>(wsS + ZOFF);
    const short* zb = wsS + ZOFF;

    // batch tiling from ws_size (deterministic -> graph-capture safe)
    auto need = [&](int nb) -> size_t {
        return (WPAD + 2ull * nb * HW * 128) * sizeof(short);
    };
    int nb = 1;
    if (ws_size >= need(4)) nb = 4;
    else if (ws_size >= need(2)) nb = 2;

    const int H2 = H / 2, W2 = W / 2;

    for (int b0 = 0; b0 < B; b0 += nb) {
        const int npx = nb * HW;
        short* X = wsS + WPAD;
        short* Y = X + (size_t)nb * HW * 128;

        const float* leftb  = left  + (size_t)b0 * HW * 64;
        const float* rightb = right + (size_t)b0 * HW * 64;
        const float* prevb  = prev  + (size_t)b0 * H2 * W2;
        float* outb = out + (size_t)b0 * HW;

        warp_costs_kernel<<<dim3(W / 64, nb * H), 256, 0, stream>>>(
            leftb, rightb, prevb, X, H, W);

        conv_mfma< 96, 128, 256, true><<<dim3(W / 128, nb * H), 256, 0, stream>>>(
            X, wsS + P1, b1, Y, zb, H, W);
        conv_mfma<128, 128, 256, true><<<dim3(W / 128, nb * H), 256, 0, stream>>>(
            Y, wsS + P2, b2, X, zb, H, W);
        conv_mfma<128,  96, 256, true><<<dim3(W / 128, nb * H), 256, 0, stream>>>(
            X, wsS + P3, b3, Y, zb, H, W);
        conv_mfma< 96,  64, 256, true><<<dim3(W / 128, nb * H), 256, 0, stream>>>(
            Y, wsS + P4, b4, X, zb, H, W);
        conv_mfma< 64,  32, 128, true><<<dim3(W / 128, nb * H), 128, 0, stream>>>(
            X, wsS + P5, b5, Y, zb, H, W);

        conv_last_kernel<<<(npx + 255) / 256, 256, 0, stream>>>(
            Y, w6, b6, outb, H, W, npx);
    }
}

// Round 9
// 881.818 us; speedup vs baseline: 1.6975x; 1.6975x over previous
//
#include <hip/hip_runtime.h>
#include <cstdint>
#include <cstddef>

// Problem dims: B=4, H=192, W=640, C=64, sr=2
// Conv chans: 69 -> 128 -> 128 -> 96 -> 64 -> 32 -> 1, 3x3 SAME, NHWC/HWIO.
//
// R10 (904us, BEST): 128px x 1-row blocks, global_load_lds ring-2 staging,
// chunk-ahead C++ B prefetch, tiled activations, lb(TPB,2).
// R12/R13 (single-buffer + tight launch_bounds / asm counted-vmcnt):
// 1377/1497us — FETCH+WRITE exploded ~5x at BOTH 4 and 3 blocks/CU ->
// blowout was structural (register starvation/spills + pinned scheduler),
// not occupancy. Reverting to R10 wholesale.
// R14 = R10 + ONE change: NT=4 layers (conv1/conv2) use 1m x 4n wave
// split (WM=1, WN=4): wave owns all 128 px, one n-tile. Per kb:
// 4 A ds_reads + 1 B load + 4 MFMAs -> B bytes/MFMA 512->256, block
// weight traffic halved, B latency amortized over 4 MFMAs.

#define LEAKY_SLOPE 0.2f

typedef float  f32x16 __attribute__((ext_vector_type(16)));
typedef short  s16x8  __attribute__((ext_vector_type(8)));
typedef short  s16x4  __attribute__((ext_vector_type(4)));

__device__ __forceinline__ unsigned short f2bf(float f) {
    unsigned u = __float_as_uint(f);
    u += 0x7FFFu + ((u >> 16) & 1u);          // round-to-nearest-even
    return (unsigned short)(u >> 16);
}
__device__ __forceinline__ float bf2f(unsigned short s) {
    return __uint_as_float(((unsigned)s) << 16);
}
__device__ __forceinline__ float leaky(float v){ return v >= 0.f ? v : LEAKY_SLOPE * v; }

// async 16B global->LDS DMA (gfx950). LDS dest = wave-uniform base + lane*16.
__device__ __forceinline__ void async16(const void* g, void* l) {
    __builtin_amdgcn_global_load_lds(
        (__attribute__((address_space(1))) void*)g,
        (__attribute__((address_space(3))) void*)l, 16, 0, 0);
}

// Bijective XCD swizzle (m204): contiguous work-chunk per XCD.
__device__ __forceinline__ int xcd_swizzle(int f, int T) {
    const int q = T >> 3, r = T & 7;
    const int xcd = f & 7, i = f >> 3;
    return (xcd < r ? xcd * (q + 1) : r * (q + 1) + (xcd - r) * q) + i;
}

// ---------------------------------------------------------------------------
// Pack HWIO fp32 weights into bf16 B-fragment order for mfma_32x32x16_bf16:
// flat = (((dydx*KB + kb)*NT + nt)*64 + lane)*8 + j
// value = w[dydx][ci = kb*16 + (lane>>5)*8 + j][co = nt*32 + (lane&31)]
// ---------------------------------------------------------------------------
__global__ __launch_bounds__(256) void pack_weights(
    const float* __restrict__ src, short* __restrict__ dst,
    int CIN, int COUT, int KB, int NT, int total)
{
    int i = blockIdx.x * 256 + threadIdx.x;
    if (i >= total) return;
    int j    = i & 7;
    int lane = (i >> 3) & 63;
    int r    = i >> 9;
    int nt = r % NT; r /= NT;
    int kb = r % KB;
    int dydx = r / KB;
    int ci = kb * 16 + ((lane >> 5) << 3) + j;
    int co = nt * 32 + (lane & 31);
    float v = (ci < CIN) ? src[((size_t)dydx * CIN + ci) * COUT + co] : 0.f;
    dst[i] = (short)f2bf(v);
}

__global__ __launch_bounds__(64) void zero_fill(short* p) {
    p[threadIdx.x] = 0;
}

// ---------------------------------------------------------------------------
// Fused upsample + warp + cost-volume. Block = 64 px (one xt) of one row.
// Output layout (tiled-96): obase + (tile*64 + px)*32 + co, tiles:
//   tile0 = left ch 0..31, tile1 = left ch 32..63,
//   tile2: co 0..4 = cost dots, co 5..31 = zero.
// ---------------------------------------------------------------------------
__global__ __launch_bounds__(256) void warp_costs_kernel(
    const float* __restrict__ left, const float* __restrict__ right,
    const float* __restrict__ prev, short* __restrict__ out,
    int H, int W)
{
    __shared__ float wt0s[68], wt1s[68];
    __shared__ int   i0s[68],  i1s[68];
    __shared__ __align__(16) short warp_s[68 * 72];  // [px -2..65][64ch]
    __shared__ __align__(16) short left_s[64 * 72];

    const int tid = threadIdx.x;
    const int w0 = blockIdx.x * 64;
    const int hh = blockIdx.y % H;
    const int bb = blockIdx.y / H;
    const int H2 = H >> 1, W2 = W >> 1;

    if (tid < 68) {
        int w = w0 - 2 + tid;
        float sy = 0.5f * (float)hh - 0.25f;
        float sx = 0.5f * (float)w  - 0.25f;
        float y0f = floorf(sy), x0f = floorf(sx);
        float fy = sy - y0f, fx = sx - x0f;
        int y0 = (int)y0f, x0 = (int)x0f;
        int y0c = min(max(y0, 0), H2 - 1), y1c = min(max(y0 + 1, 0), H2 - 1);
        int x0c = min(max(x0, 0), W2 - 1), x1c = min(max(x0 + 1, 0), W2 - 1);
        const float* pb = prev + (size_t)bb * H2 * W2;
        float p00 = pb[y0c * W2 + x0c], p01 = pb[y0c * W2 + x1c];
        float p10 = pb[y1c * W2 + x0c], p11 = pb[y1c * W2 + x1c];
        float disp = (1.f - fy) * ((1.f - fx) * p00 + fx * p01)
                   + fy * ((1.f - fx) * p10 + fx * p11);
        float cx = (float)w + disp;
        float xf0 = floorf(cx), xf1 = xf0 + 1.f;
        float xmax = (float)(W - 1);
        float x0s = fminf(fmaxf(xf0, 0.f), xmax);
        float x1s = fminf(fmaxf(xf1, 0.f), xmax);
        wt0s[tid] = (xf1 - cx) * (xf0 == x0s ? 1.f : 0.f);
        wt1s[tid] = (cx - xf0) * (xf1 == x1s ? 1.f : 0.f);
        i0s[tid] = (int)x0s;
        i1s[tid] = (int)x1s;
    }
    __syncthreads();

    const float* rrow = right + (size_t)(bb * H + hh) * W * 64;
    const float* lrow = left  + (size_t)(bb * H + hh) * W * 64;
    const size_t obase = ((size_t)(bb * H + hh) * W + w0) * 96;

    for (int u = tid; u < 68 * 16; u += 256) {
        int px = u >> 4, c4 = (u & 15) * 4;
        float a = wt0s[px], b = wt1s[px];
        const float4 r0 = *(const float4*)(rrow + (size_t)i0s[px] * 64 + c4);
        const float4 r1 = *(const float4*)(rrow + (size_t)i1s[px] * 64 + c4);
        s16x4 o;
        o[0] = (short)f2bf(a * r0.x + b * r1.x);
        o[1] = (short)f2bf(a * r0.y + b * r1.y);
        o[2] = (short)f2bf(a * r0.z + b * r1.z);
        o[3] = (short)f2bf(a * r0.w + b * r1.w);
        *(s16x4*)(warp_s + px * 72 + c4) = o;
    }
    for (int u = tid; u < 64 * 16; u += 256) {
        int px = u >> 4, c4 = (u & 15) * 4;
        const float4 l = *(const float4*)(lrow + ((size_t)(w0 + px)) * 64 + c4);
        s16x4 o;
        o[0] = (short)f2bf(l.x);
        o[1] = (short)f2bf(l.y);
        o[2] = (short)f2bf(l.z);
        o[3] = (short)f2bf(l.w);
        *(s16x4*)(left_s + px * 72 + c4) = o;
        // tiled store: tile = c4>>5, co = c4&31
        *(s16x4*)(out + obase + ((size_t)((c4 >> 5) * 64 + px)) * 32 + (c4 & 31)) = o;
    }
    // zero tile2 (ch 64..95) fully: 2048 contiguous shorts at obase+4096
    {
        s16x8 z = {0,0,0,0,0,0,0,0};
        *(s16x8*)(out + obase + 4096 + (size_t)tid * 8) = z;
    }
    __syncthreads();

    // cost dots: 320 (px,d) tasks -> tile2 co d (ordered after zero via barrier)
    for (int u = tid; u < 64 * 5; u += 256) {
        int px = u / 5, d = u - px * 5;
        int x = w0 + px + d - 2;
        float s = 0.f;
        if (x >= 0 && x < W) {
            const short* lp = left_s + px * 72;
            const short* wq = warp_s + (px + d) * 72;
#pragma unroll
            for (int c8 = 0; c8 < 8; ++c8) {
                s16x8 l8 = *(const s16x8*)(lp + c8 * 8);
                s16x8 w8 = *(const s16x8*)(wq + c8 * 8);
#pragma unroll
                for (int k = 0; k < 8; ++k)
                    s += bf2f((unsigned short)l8[k]) * bf2f((unsigned short)w8[k]);
            }
        }
        out[obase + 4096 + (size_t)px * 32 + d] = (short)f2bf(s * (1.f / 64.f));
    }
}

// ---------------------------------------------------------------------------
// bf16 MFMA 3x3 conv (implicit GEMM, mfma_f32_32x32x16_bf16).
// Block = 128 px of one row x all COUT (R10 geometry). Wave split:
//   NT=4 (conv1/2): WM=1 x WN=4 -> wave owns all 4 m-tiles, 1 n-tile.
//     Per kb: 4 A ds_reads + 1 B load + 4 MFMAs (B 256 B/MFMA).
//   NT=3 (conv3):   WM=2 x WN=2, NTW=2 (tile 3 phantom-skipped).
//   NT=2 (conv4):   WM=2 x WN=2, NTW=1.  NT=1 (conv5): TPB=128, WM=2.
// A rows: ring-2 exact-size LDS buffers via global_load_lds (issued one dy
// ahead; __syncthreads' vmcnt(0) publishes). XOR swizzle folded into
// per-lane DMA source; phantom-channel slots skipped (never read).
// B weights: one (dy,dx) chunk prefetched ahead (bA/bB, literal indices).
// Activations tiled [h][xt][cotile][px64][co32]; tiled full-line stores.
// ---------------------------------------------------------------------------
template <int CINP, int COUT, int TPB, bool RELU>
__global__ __launch_bounds__(TPB, 2) void conv_mfma(
    const short* __restrict__ in, const short* __restrict__ wp,
    const float* __restrict__ bias, short* __restrict__ out,
    const short* __restrict__ zerobuf, int H, int W)
{
    constexpr int KB   = CINP / 16;                  // K-steps per (dy,dx)
    constexpr int NT   = COUT / 32;                  // n-tiles total
    constexpr int TI   = CINP / 32;                  // input co-tiles
    constexpr int CIN8 = CINP / 8;
    constexpr int SL8  = (CIN8 == 12) ? 16 : CIN8;   // LDS ch8-slots/px (pow2)
    constexpr int SH   = (SL8 == 16) ? 4 : 3;        // log2(SL8)
    constexpr int WN   = (NT >= 4) ? 4 : (NT >= 2) ? 2 : 1;  // n-split ways
    constexpr int WM   = (TPB / 64) / WN;            // m-split ways
    constexpr int MT   = 4 / WM;                     // m-tiles per wave
    constexpr int NTW  = (NT + WN - 1) / WN;         // n-tiles per wave
    constexpr int TASKS = 130 * SL8;                 // 16B stage tasks/row
    constexpr int NITER = (TASKS + TPB - 1) / TPB;
    constexpr int BUFS  = TASKS * 8;                 // shorts per row buffer
    __shared__ __align__(16) short lds[2 * BUFS];

    const int tid  = threadIdx.x;
    const int lane = tid & 63;
    const int wave = tid >> 6;
    const int wn   = wave % WN;
    const int wm   = wave / WN;
    const int l31  = lane & 31;
    const int lhi  = lane >> 5;

    // XCD-aware remap (bijective): contiguous rows per XCD, x fastest.
    const int nbx  = gridDim.x;
    const int work = xcd_swizzle(blockIdx.y * nbx + blockIdx.x,
                                 nbx * gridDim.y);
    const int w0 = (work % nbx) * 128;
    const int by = work / nbx;
    const int hh = by % H;
    const int bb = by / H;

    // stage input row H_ into ring buffer SEL. Tiled source layout:
    // addr = rowbase + ((x>>6)*TI + (sc>>2))*2048 + (x&63)*32 + (sc&3)*8
#define ISSUE_STAGE(SEL, H_) do {                                          \
        const int h_ = (H_);                                               \
        const bool rowok_ = (h_ >= 0) && (h_ < H);                         \
        const size_t rb_ = (size_t)(bb * H + (rowok_ ? h_ : 0)) * W * CINP;\
        short* lb_ = lds + (SEL) * BUFS;                                   \
        _Pragma("unroll")                                                  \
        for (int k_ = 0; k_ < NITER; ++k_) {                               \
            const int u_  = tid + k_ * TPB;                                \
            const int px_ = u_ >> SH;                                      \
            const int sc_ = (u_ & (SL8 - 1)) ^ (px_ & 7);                  \
            const int x_  = w0 - 1 + px_;                                  \
            if (u_ < TASKS && sc_ < CIN8) {                                \
                const bool ok_ = rowok_ && (x_ >= 0) && (x_ < W);          \
                const int xc_ = ok_ ? x_ : 0;                              \
                const short* g_ = ok_                                      \
                    ? (in + rb_ + ((xc_ >> 6) * TI + (sc_ >> 2)) * 2048    \
                             + (xc_ & 63) * 32 + (sc_ & 3) * 8)            \
                    : zerobuf;                                             \
                async16(g_, lb_ + (size_t)(u_ - lane) * 8);                \
            }                                                              \
        }                                                                  \
    } while (0)

    // load B chunk (DY,DX) into named buffer BUF (literal indices only).
#define LOADB(BUF, DY, DX) do {                                            \
        const short* wdx_ = wlane + (size_t)(((DY) * 3 + (DX)) * KB) * NT * 512; \
        _Pragma("unroll")                                                  \
        for (int kb_ = 0; kb_ < KB; ++kb_)                                 \
        _Pragma("unroll")                                                  \
        for (int j_ = 0; j_ < NTW; ++j_) {                                 \
            const int tile_ = wn * NTW + j_;                               \
            if (tile_ < NT)                                                \
                BUF[kb_][j_] = *(const s16x8*)(wdx_ + (size_t)(kb_ * NT + tile_) * 512); \
        }                                                                  \
    } while (0)

    // run KB k-steps of one dx using B buffer BUF against abuf rows.
#define MFMA_STEP(BUF, DX) do {                                            \
        _Pragma("unroll")                                                  \
        for (int kb_ = 0; kb_ < KB; ++kb_) {                               \
            const int c8r_ = kb_ * 2 + lhi;                                \
            s16x8 a_[MT];                                                  \
            _Pragma("unroll")                                              \
            for (int mt_ = 0; mt_ < MT; ++mt_) {                           \
                const int px_ = (wm * MT + mt_) * 32 + l31 + (DX);         \
                a_[mt_] = *(const s16x8*)(&abuf[(px_ * SL8 + (c8r_ ^ (px_ & 7))) * 8]); \
            }                                                              \
            _Pragma("unroll")                                              \
            for (int j_ = 0; j_ < NTW; ++j_) {                             \
                if (wn * NTW + j_ >= NT) continue;                         \
                _Pragma("unroll")                                          \
                for (int mt_ = 0; mt_ < MT; ++mt_)                         \
                    acc[mt_][j_] = __builtin_amdgcn_mfma_f32_32x32x16_bf16( \
                        a_[mt_], BUF[kb_][j_], acc[mt_][j_], 0, 0, 0);     \
            }                                                              \
        }                                                                  \
    } while (0)

    f32x16 acc[MT][NTW];
#pragma unroll
    for (int mt = 0; mt < MT; ++mt)
#pragma unroll
        for (int j = 0; j < NTW; ++j)
#pragma unroll
            for (int r = 0; r < 16; ++r) acc[mt][j][r] = 0.f;

    const short* wlane = wp + (size_t)lane * 8;
    s16x8 bA[KB][NTW], bB[KB][NTW];

    // prologue: stage row dy=0 (hh-1) into buf0; prefetch B chunk 0.
    ISSUE_STAGE(0, hh - 1);
    LOADB(bA, 0, 0);

#pragma unroll
    for (int dy = 0; dy < 3; ++dy) {
        // __syncthreads drains vmcnt(0) (stage DMA done) + barrier:
        // publishes buf[dy&1]; safe to overwrite buf[(dy+1)&1] after.
        __syncthreads();
        if (dy < 2) ISSUE_STAGE((dy + 1) & 1, hh + dy);
        const short* abuf = lds + (dy & 1) * BUFS;
#pragma unroll
        for (int dx = 0; dx < 3; ++dx) {
            const int c = dy * 3 + dx;     // chunk index 0..8, literal
            if ((c & 1) == 0) {
                if (c < 8) LOADB(bB, (c + 1) / 3, (c + 1) % 3);
                MFMA_STEP(bA, dx);
            } else {
                if (c < 8) LOADB(bA, (c + 1) / 3, (c + 1) % 3);
                MFMA_STEP(bB, dx);
            }
        }
    }
#undef ISSUE_STAGE
#undef LOADB
#undef MFMA_STEP

    // epilogue: tiled stores. C/D: co=l31, px64=(v&3)+8*(v>>2)+4*lhi.
    // addr = outrow + ((xt*NT + tile)*64 + px64)*32 + co -> full-line
    // same-wave writebacks.
    const size_t outrow = (size_t)(bb * H + hh) * W * COUT;
    const int xtb = w0 >> 6;
#pragma unroll
    for (int j = 0; j < NTW; ++j) {
        const int tile = wn * NTW + j;
        if (tile >= NT) continue;
        const float bv = bias[tile * 32 + l31];
#pragma unroll
        for (int mt = 0; mt < MT; ++mt) {
            const int mtile = wm * MT + mt;
            const int xt   = xtb + (mtile >> 1);
            const int pxb  = (mtile & 1) * 32 + 4 * lhi;
            const size_t tbase = outrow + (size_t)((xt * NT + tile) * 64) * 32;
#pragma unroll
            for (int v = 0; v < 16; ++v) {
                const int px64 = pxb + (v & 3) + 8 * (v >> 2);
                float val = acc[mt][j][v] + bv;
                if (RELU) val = leaky(val);
                out[tbase + px64 * 32 + l31] = (short)f2bf(val);
            }
        }
    }
}

// ---------------------------------------------------------------------------
// Final conv 32 -> 1, linear, bf16 in / fp32 out. One thread per pixel.
// (tiled-32 layout == NHWC, so addressing unchanged.)
// ---------------------------------------------------------------------------
__global__ __launch_bounds__(256) void conv_last_kernel(
    const short* __restrict__ in, const float* __restrict__ wgt,
    const float* __restrict__ bias, float* __restrict__ out,
    int H, int W, int npx)
{
    int blk = xcd_swizzle(blockIdx.x, gridDim.x);
    int idx = blk * 256 + threadIdx.x;
    if (idx >= npx) return;
    int w = idx % W;
    int t = idx / W;
    int h = t % H;
    int b = t / H;

    float acc = bias[0];
#pragma unroll
    for (int dy = 0; dy < 3; ++dy) {
        int hy = h + dy - 1;
        if (hy < 0 || hy >= H) continue;
#pragma unroll
        for (int dx = 0; dx < 3; ++dx) {
            int x = w + dx - 1;
            if (x < 0 || x >= W) continue;
            const short* p = in + ((size_t)(b * H + hy) * W + x) * 32;
            const float* wk = wgt + (dy * 3 + dx) * 32;
#pragma unroll
            for (int c8 = 0; c8 < 4; ++c8) {
                s16x8 v = *(const s16x8*)(p + c8 * 8);
#pragma unroll
                for (int k = 0; k < 8; ++k)
                    acc += bf2f((unsigned short)v[k]) * wk[c8 * 8 + k];
            }
        }
    }
    out[idx] = acc;
}

// ---------------------------------------------------------------------------
extern "C" void kernel_launch(void* const* d_in, const int* in_sizes, int n_in,
                              void* d_out, int out_size, void* d_ws, size_t ws_size,
                              hipStream_t stream)
{
    constexpr int B = 4, H = 192, W = 640;
    constexpr int HW = H * W;          // 122880

    const float* left  = (const float*)d_in[0];
    const float* right = (const float*)d_in[1];
    const float* prev  = (const float*)d_in[2];
    const float* w1 = (const float*)d_in[4];
    const float* b1 = (const float*)d_in[5];
    const float* w2 = (const float*)d_in[6];
    const float* b2 = (const float*)d_in[7];
    const float* w3 = (const float*)d_in[8];
    const float* b3 = (const float*)d_in[9];
    const float* w4 = (const float*)d_in[10];
    const float* b4 = (const float*)d_in[11];
    const float* w5 = (const float*)d_in[12];
    const float* b5 = (const float*)d_in[13];
    const float* w6 = (const float*)d_in[14];
    const float* b6 = (const float*)d_in[15];
    float* out = (float*)d_out;

    // Packed-weight region (shorts), then bf16 activation ping-pong X/Y.
    constexpr int S1 = 9 * 6 * 4 * 512;   // conv1: CINP 96,  COUT 128
    constexpr int S2 = 9 * 8 * 4 * 512;   // conv2: 128 -> 128
    constexpr int S3 = 9 * 8 * 3 * 512;   // conv3: 128 -> 96
    constexpr int S4 = 9 * 6 * 2 * 512;   // conv4: 96  -> 64
    constexpr int S5 = 9 * 4 * 1 * 512;   // conv5: 64  -> 32
    constexpr int P1 = 0, P2 = P1 + S1, P3 = P2 + S2, P4 = P3 + S3, P5 = P4 + S4;
    constexpr size_t WPAD = 524288;       // 1 MiB reserved (in shorts)
    constexpr size_t ZOFF = WPAD - 64;    // 128B zero region for DMA redirect

    short* wsS = (short*)d_ws;
    pack_weights<<<(S1 + 255) / 256, 256, 0, stream>>>(w1, wsS + P1,  69, 128, 6, 4, S1);
    pack_weights<<<(S2 + 255) / 256, 256, 0, stream>>>(w2, wsS + P2, 128, 128, 8, 4, S2);
    pack_weights<<<(S3 + 255) / 256, 256, 0, stream>>>(w3, wsS + P3, 128,  96, 8, 3, S3);
    pack_weights<<<(S4 + 255) / 256, 256, 0, stream>>>(w4, wsS + P4,  96,  64, 6, 2, S4);
    pack_weights<<<(S5 + 255) / 256, 256, 0, stream>>>(w5, wsS + P5,  64,  32, 4, 1, S5);
    zero_fill<<<1, 64, 0, stream>>>(wsS + ZOFF);
    const short* zb = wsS + ZOFF;

    // batch tiling from ws_size (deterministic -> graph-capture safe)
    auto need = [&](int nb) -> size_t {
        return (WPAD + 2ull * nb * HW * 128) * sizeof(short);
    };
    int nb = 1;
    if (ws_size >= need(4)) nb = 4;
    else if (ws_size >= need(2)) nb = 2;

    const int H2 = H / 2, W2 = W / 2;

    for (int b0 = 0; b0 < B; b0 += nb) {
        const int npx = nb * HW;
        short* X = wsS + WPAD;
        short* Y = X + (size_t)nb * HW * 128;

        const float* leftb  = left  + (size_t)b0 * HW * 64;
        const float* rightb = right + (size_t)b0 * HW * 64;
        const float* prevb  = prev  + (size_t)b0 * H2 * W2;
        float* outb = out + (size_t)b0 * HW;

        warp_costs_kernel<<<dim3(W / 64, nb * H), 256, 0, stream>>>(
            leftb, rightb, prevb, X, H, W);

        conv_mfma< 96, 128, 256, true><<<dim3(W / 128, nb * H), 256, 0, stream>>>(
            X, wsS + P1, b1, Y, zb, H, W);
        conv_mfma<128, 128, 256, true><<<dim3(W / 128, nb * H), 256, 0, stream>>>(
            Y, wsS + P2, b2, X, zb, H, W);
        conv_mfma<128,  96, 256, true><<<dim3(W / 128, nb * H), 256, 0, stream>>>(
            X, wsS + P3, b3, Y, zb, H, W);
        conv_mfma< 96,  64, 256, true><<<dim3(W / 128, nb * H), 256, 0, stream>>>(
            Y, wsS + P4, b4, X, zb, H, W);
        conv_mfma< 64,  32, 128, true><<<dim3(W / 128, nb * H), 128, 0, stream>>>(
            X, wsS + P5, b5, Y, zb, H, W);

        conv_last_kernel<<<(npx + 255) / 256, 256, 0, stream>>>(
            Y, w6, b6, outb, H, W, npx);
    }
}